// Round 1
// baseline (35.752 us; speedup 1.0000x reference)
//
#include <hip/hip_runtime.h>

// loss = -1.5 * sum_c |S_c|^2 + Q + 0.5 * |T|^2
//   S_c = sum of feat rows with label c, T = total row sum, Q = sum feat^2.
// ws layout (floats): [0 .. NCLS*DIMS) class sums, [NCLS*DIMS] Q accumulator.

#define DIMS 256
#define NCLS 128          // labels are [0,100); padded to pow2 for safe masking
#define ACC_BLOCKS 256

__global__ __launch_bounds__(256) void contrast_accum(
    const float* __restrict__ feat, const int* __restrict__ label,
    float* __restrict__ ws, int B) {
  const int t = threadIdx.x;                  // dim index 0..255
  const int rowsPerBlock = B / ACC_BLOCKS;    // 32 for B=8192
  const int r0 = blockIdx.x * rowsPerBlock;
  const int r1 = r0 + rowsPerBlock;
  float q = 0.f;
  for (int r = r0; r < r1; ++r) {
    const int c = label[r] & (NCLS - 1);      // uniform per block -> s_load
    const float v = feat[(size_t)r * DIMS + t];
    q += v * v;
    atomicAdd(&ws[c * DIMS + t], v);
  }
  // block-reduce q into global Q accumulator
  __shared__ float red[256];
  red[t] = q;
  __syncthreads();
  #pragma unroll
  for (int s = 128; s > 0; s >>= 1) {
    if (t < s) red[t] += red[t + s];
    __syncthreads();
  }
  if (t == 0) atomicAdd(&ws[NCLS * DIMS], red[0]);
}

__global__ __launch_bounds__(256) void contrast_finish(
    const float* __restrict__ ws, float* __restrict__ out) {
  const int t = threadIdx.x;                  // dim index
  float Tt = 0.f, ssq = 0.f;
  #pragma unroll 4
  for (int c = 0; c < NCLS; ++c) {
    const float v = ws[c * DIMS + t];
    Tt += v;
    ssq += v * v;
  }
  __shared__ float redT[256];
  __shared__ float redS[256];
  redT[t] = Tt * Tt;                          // contributes to |T|^2
  redS[t] = ssq;                              // contributes to sum_c |S_c|^2
  __syncthreads();
  #pragma unroll
  for (int s = 128; s > 0; s >>= 1) {
    if (t < s) { redT[t] += redT[t + s]; redS[t] += redS[t + s]; }
    __syncthreads();
  }
  if (t == 0) {
    const float Q = ws[NCLS * DIMS];
    out[0] = -1.5f * redS[0] + Q + 0.5f * redT[0];
  }
}

extern "C" void kernel_launch(void* const* d_in, const int* in_sizes, int n_in,
                              void* d_out, int out_size, void* d_ws, size_t ws_size,
                              hipStream_t stream) {
  (void)n_in; (void)out_size; (void)ws_size;
  const float* feat = (const float*)d_in[0];
  const int* label = (const int*)d_in[1];
  float* ws = (float*)d_ws;
  const int B = in_sizes[1];                  // 8192 labels

  hipMemsetAsync(d_ws, 0, (NCLS * DIMS + 1) * sizeof(float), stream);
  contrast_accum<<<ACC_BLOCKS, 256, 0, stream>>>(feat, label, ws, B);
  contrast_finish<<<1, 256, 0, stream>>>(ws, (float*)d_out);
}